// Round 11
// baseline (225.700 us; speedup 1.0000x reference)
//
#include <hip/hip_runtime.h>
#include <stdint.h>

typedef unsigned long long u64;
typedef unsigned int u32;

#define NUM_B 32
#define NUM_P 76800
#define TOPK 1500
#define NBINS 4096   // linear bins: bin = min(int(s*4096), 4095)
#define CAP 2048
#define NWORDS 24    // ceil(1500/64) u64 words per mask row == number of 64-row tiles
#define NCHUNK 6     // ceil(1500/256) row chunks for mask grid
#define CPAD 32      // counts padded to 128 B to kill same-line atomic serialization
#define HSLICES 8    // private histogram slices per batch (no global atomics)
#define HCHUNK (NUM_P / HSLICES)   // 9600 priors per slice

__device__ __forceinline__ u32 fbits(float f) { return __float_as_uint(f); }
// Monotone non-decreasing in s => threshold-bin selection is order-correct.
__device__ __forceinline__ int binOf(float s) {
    int b = (int)(s * (float)NBINS);
    return (b > NBINS - 1) ? NBINS - 1 : b;
}
// wave-uniform lane read of a u64 register
__device__ __forceinline__ u64 readlane64(u64 v, int l) {
    u32 lo = (u32)__builtin_amdgcn_readlane((int)(u32)(v & 0xffffffffu), l);
    u32 hi = (u32)__builtin_amdgcn_readlane((int)(u32)(v >> 32), l);
    return ((u64)hi << 32) | lo;
}

// ---------------- zero counts + output + sscore/sbox ----------------
__global__ void zero_kernel(u32* a, int n, u32* c, int nc, u32* d, int nd) {
    int i = blockIdx.x * blockDim.x + threadIdx.x;
    int stride = gridDim.x * blockDim.x;
    for (int t = i; t < n; t += stride) a[t] = 0;
    for (int t = i; t < nc; t += stride) c[t] = 0;
    for (int t = i; t < nd; t += stride) d[t] = 0;
}

// ---------------- histogram: LDS-private per (batch, slice), full overwrite ----------------
__global__ __launch_bounds__(256) void hist_kernel(const float4* __restrict__ conf4,
                                                   u32* __restrict__ hist) {
    int c = blockIdx.x, b = blockIdx.y, tid = threadIdx.x;
    __shared__ u32 h[NBINS];
    for (int i = tid; i < NBINS; i += 256) h[i] = 0;
    __syncthreads();
    const float4* base = conf4 + (size_t)b * (NUM_P / 2) + (size_t)c * (HCHUNK / 2);
    for (int i = tid; i < HCHUNK / 2; i += 256) {
        float4 v = base[i];           // 2 priors: (c0,c1,c0,c1); class-1 = .y/.w
        if (v.y > 0.01f) atomicAdd(&h[binOf(v.y)], 1u);
        if (v.w > 0.01f) atomicAdd(&h[binOf(v.w)], 1u);
    }
    __syncthreads();
    u32* outp = hist + ((size_t)b * HSLICES + c) * NBINS;
    for (int i = tid; i < NBINS; i += 256) outp[i] = h[i];
}

// ---------------- find per-batch threshold bin: smallest bin T with suffix count >= TOPK ----
__global__ void thresh_kernel(const u32* __restrict__ hist, int* __restrict__ tbin) {
    int b = blockIdx.x;
    int tid = threadIdx.x;
    const u32* hb = hist + (size_t)b * HSLICES * NBINS;
    __shared__ u32 vals[256];
    __shared__ int s_min;
    u32 total = 0;
    for (int c = 0; c < NBINS / 256; ++c) {
        if (tid == 0) s_min = 256;
        int bin = NBINS - 1 - (c * 256 + tid);
        u32 v = 0;
#pragma unroll
        for (int s = 0; s < HSLICES; ++s) v += hb[(size_t)s * NBINS + bin];
        __syncthreads();
        vals[tid] = v;
        __syncthreads();
        for (int off = 1; off < 256; off <<= 1) {
            u32 add = (tid >= off) ? vals[tid - off] : 0;
            __syncthreads();
            vals[tid] += add;
            __syncthreads();
        }
        u32 cum = total + vals[tid];
        if (cum >= TOPK) atomicMin(&s_min, tid);
        __syncthreads();
        if (s_min < 256) {
            if (tid == 0) tbin[b] = NBINS - 1 - (c * 256 + s_min);
            return;
        }
        total += vals[255];
    }
    if (tid == 0) tbin[b] = 0;
}

// ---------------- compact candidate keys: float4 loads, padded counters ----------------
__global__ __launch_bounds__(256) void compact_kernel(
    const float4* __restrict__ conf4, const int* __restrict__ tbin,
    u32* __restrict__ counts, u64* __restrict__ keys) {
    int b = blockIdx.y;
    int tid = threadIdx.x;
    int lane = tid & 63, wave = tid >> 6;
    int f4 = blockIdx.x * 256 + tid;            // float4 index within batch (2 priors)
    float4 c = conf4[(size_t)b * (NUM_P / 2) + f4];
    int tb = tbin[b];
    int p0 = f4 * 2, p1 = p0 + 1;
    bool v0 = (c.y > 0.01f) && (binOf(c.y) >= tb);
    bool v1 = (c.w > 0.01f) && (binOf(c.w) >= tb);

    u64 m0 = __ballot(v0), m1 = __ballot(v1);
    u32 c0 = (u32)__popcll(m0);
    u64 below = (1ULL << lane) - 1ULL;
    u32 off0 = (u32)__popcll(m0 & below);
    u32 off1 = c0 + (u32)__popcll(m1 & below);
    u32 wtot = c0 + (u32)__popcll(m1);

    __shared__ u32 wcnt[4];
    __shared__ u32 s_base;
    if (lane == 0) wcnt[wave] = wtot;
    __syncthreads();
    if (tid == 0) {
        u32 tot = wcnt[0] + wcnt[1] + wcnt[2] + wcnt[3];
        s_base = (tot > 0) ? atomicAdd(&counts[(size_t)b * CPAD], tot) : 0u;
    }
    __syncthreads();
    u32 woff = 0;
    for (int w = 0; w < wave; ++w) woff += wcnt[w];
    if (v0) {
        u32 pos = s_base + woff + off0;
        if (pos < CAP) keys[(size_t)b * CAP + pos] = ((u64)fbits(c.y) << 32) | (u32)(~p0);
    }
    if (v1) {
        u32 pos = s_base + woff + off1;
        if (pos < CAP) keys[(size_t)b * CAP + pos] = ((u64)fbits(c.w) << 32) | (u32)(~p1);
    }
}

// ---------------- rank-by-count (replaces bitonic sort) + gather+decode boxes ----------
__global__ __launch_bounds__(256) void rank_decode_kernel(
    const u64* __restrict__ keys, const u32* __restrict__ counts,
    const float* __restrict__ loc, const float* __restrict__ prior,
    float* __restrict__ sscore, float* __restrict__ sbox) {
#pragma clang fp contract(off)
    int blk = blockIdx.x, b = blockIdx.y, tid = threadIdx.x;
    __shared__ u64 k[CAP];
    int n = (int)min(counts[(size_t)b * CPAD], (u32)CAP);
    for (int t = tid; t < CAP; t += 256)
        k[t] = (t < n) ? keys[(size_t)b * CAP + t] : 0ULL;
    __syncthreads();

    int t = blk * 256 + tid;
    u64 mykey = k[t];
    if (mykey == 0ULL) return;   // empty slot (valid keys have score bits != 0)

    u32 rank = 0;
#pragma unroll 8
    for (int j = 0; j < CAP; ++j) rank += (k[j] > mykey) ? 1u : 0u;

    if (rank < TOPK) {
        u32 pidx = ~(u32)mykey;
        float sc = __uint_as_float((u32)(mykey >> 32));
        const float* lp = &loc[((size_t)b * NUM_P + pidx) * 4];
        const float* pp = &prior[(size_t)pidx * 4];
        float lx = lp[0], ly = lp[1], lw = lp[2], lh = lp[3];
        float pcx = pp[0], pcy = pp[1], pw = pp[2], ph = pp[3];
        float cx = pcx + (lx * 0.1f) * pw;
        float cy = pcy + (ly * 0.1f) * ph;
        float w  = pw * expf(lw * 0.2f);
        float h  = ph * expf(lh * 0.2f);
        float x1 = cx - w * 0.5f;
        float y1 = cy - h * 0.5f;
        float x2 = x1 + w;
        float y2 = y1 + h;
        sscore[(size_t)b * TOPK + rank] = sc;
        float* bx = &sbox[((size_t)b * TOPK + rank) * 4];
        bx[0] = x1; bx[1] = y1; bx[2] = x2; bx[3] = y2;
    }
}

// ---------------- NMS phase 1: suppression bitmask — transposed, balanced, div-free ----
// Exact predicate: div_RN(inter,denom) > 0.2f  <=>  (double)inter >= MID*(double)denom
// where MID = midpoint(0.2f, nextafter(0.2f)). MID has 25 bits, denom 24 ->
// MID*denom exact in double; comparison exact (tie->even rounds up at 0x3E4CCCCE).
// j>i hoisted to a per-row jmask applied once.
__global__ __launch_bounds__(256) void mask_kernel(
    const float* __restrict__ sbox, u64* __restrict__ mask) {
#pragma clang fp contract(off)
    int w = blockIdx.x, c = blockIdx.y, b = blockIdx.z, tid = threadIdx.x;
    int i = c * 256 + tid;
    __shared__ float4 cbox[64];
    __shared__ float car[64];
    bool blk_live = (w * 64 + 63) > (c * 256);   // any row in chunk needs this word
    if (blk_live) {
        if (tid < 64) {
            int j = w * 64 + tid;
            float4 bx = make_float4(0.f, 0.f, 0.f, 0.f);
            if (j < TOPK) bx = ((const float4*)sbox)[(size_t)b * TOPK + j];
            cbox[tid] = bx;
            car[tid] = (bx.z - bx.x) * (bx.w - bx.y);
        }
        __syncthreads();
    }
    u64 m = 0;
    if (blk_live && i < TOPK && (w * 64 + 63) > i) {
        const double MID = 0.5 * ((double)__uint_as_float(0x3E4CCCCDu) +
                                  (double)__uint_as_float(0x3E4CCCCEu));
        const float4 bx = ((const float4*)sbox)[(size_t)b * TOPK + i];
        float x1i = bx.x, y1i = bx.y, x2i = bx.z, y2i = bx.w;
        float ai = (x2i - x1i) * (y2i - y1i);
        u64 jmask = (i < w * 64) ? ~0ULL : (~0ULL << (i - w * 64 + 1));
        for (int j2 = 0; j2 < 64; ++j2) {
            float4 cb = cbox[j2];
            float xx1 = fmaxf(cb.x, x1i);
            float yy1 = fmaxf(cb.y, y1i);
            float xx2 = fminf(cb.z, x2i);
            float yy2 = fminf(cb.w, y2i);
            float iw = fmaxf(xx2 - xx1, 0.0f);
            float ih = fmaxf(yy2 - yy1, 0.0f);
            float inter = iw * ih;
            float denom = (car[j2] + ai) - inter;
            if ((double)inter >= MID * (double)denom) m |= (1ULL << j2);
        }
        m &= jmask;
    }
    if (i < TOPK)
        mask[((size_t)b * NWORDS + w) * TOPK + i] = m;
}

// ---------------- NMS phase 2: tiled serial sweep, one wave per batch ----------------
// Rows live in LDS (2 buffers, padded to 65 for <=2-way bank conflicts); staging is
// fixed-count coalesced loads with rolling VGPRs (no spillable long-lived ring).
// Greedy diag stays in a 3-deep register ring (1 coalesced load/tile, readlane64).
// Tile order: issue loads(T+1) -> greedy(T) -> apply(T, LDS) -> ds_write(T+1) -> sync.
__global__ __launch_bounds__(64) void sweep_kernel(
    const u64* __restrict__ mask, const float* __restrict__ sscore,
    const float* __restrict__ sbox, float* __restrict__ out) {
    int b = blockIdx.x, lane = threadIdx.x;

    // initial active bitmap from validity (score > 0); lane w owns act word w
    u64 act = 0;
    for (int c = 0; c < NWORDS; ++c) {
        int r = c * 64 + lane;
        bool v = (r < TOPK) && (sscore[(size_t)b * TOPK + r] > 0.0f);
        u64 m = __ballot(v);
        if (lane == c) act = m;
    }

    const u64* mbase = mask + (size_t)b * NWORDS * TOPK;   // word w, row r: mbase[w*TOPK+r]

    __shared__ u64 rowbuf[2][NWORDS][65];   // [buf][word][row(+pad)]

    // preamble: stage tile 0 into buf 0 (rows = lane, all < TOPK)
    {
        u64 sv[NWORDS];
#pragma unroll
        for (int w = 0; w < NWORDS; ++w) sv[w] = mbase[(size_t)w * TOPK + lane];
#pragma unroll
        for (int w = 0; w < NWORDS; ++w) rowbuf[0][w][lane] = sv[w];
    }
    u64 d0 = mbase[(size_t)0 * TOPK + lane];         // diag word, tile 0
    u64 d1 = mbase[(size_t)1 * TOPK + 64 + lane];    // diag word, tile 1
    __syncthreads();

    for (int T = 0; T < NWORDS; ++T) {
        // prefetch diag for T+2 (register ring)
        u64 d2 = 0;
        if (T + 2 < NWORDS) {
            int rr = (T + 2) * 64 + lane;
            if (rr < TOPK) d2 = mbase[(size_t)(T + 2) * TOPK + rr];
        }
        // issue staging loads for tile T+1 (fixed 24, coalesced; w<T+1 rows are 0 in mem)
        u64 sv[NWORDS];
        bool stage = (T + 1 < NWORDS);
        int rr1 = (T + 1) * 64 + lane;
        bool vr = stage && (rr1 < TOPK);
#pragma unroll
        for (int w = 0; w < NWORDS; ++w)
            sv[w] = vr ? mbase[(size_t)w * TOPK + rr1] : 0ULL;

        // greedy on register diag for tile T
        u64 actw = readlane64(act, T);
        u64 kept = 0, rem = actw;
        while (rem) {
            int i2 = __ffsll(rem) - 1;
            kept |= (1ULL << i2);
            rem &= rem - 1;
            rem &= ~readlane64(d0, i2);
        }
        if (lane == T) act = kept;

        // apply kept rows from buf[T&1] (written last tile; no vm dependence)
        if (lane > T && lane < NWORDS) {
            u64 kb = kept;
            while (kb) {
                int r = __ffsll(kb) - 1;
                kb &= kb - 1;
                act &= ~rowbuf[T & 1][lane][r];
            }
        }

        // commit staging writes for tile T+1 (absorbs load latency), then sync
        if (stage) {
#pragma unroll
            for (int w = 0; w < NWORDS; ++w) rowbuf[(T + 1) & 1][w][lane] = sv[w];
        }
        __syncthreads();
        d0 = d1; d1 = d2;
    }

    // epilogue: act == keep bitmap; rank by prefix popcount, write compacted rows
    __shared__ u64 aw[NWORDS];
    __shared__ u32 pfx[NWORDS + 1];
    if (lane < NWORDS) aw[lane] = act;
    __syncthreads();
    if (lane == 0) {
        u32 acc = 0;
        for (int wd = 0; wd < NWORDS; ++wd) { pfx[wd] = acc; acc += (u32)__popcll(aw[wd]); }
        pfx[NWORDS] = acc;
    }
    __syncthreads();
    for (int r = lane; r < TOPK; r += 64) {
        int wd = r >> 6;
        u64 word = aw[wd];
        if ((word >> (r & 63)) & 1ULL) {
            u32 rank = pfx[wd] + (u32)__popcll(word & ((1ULL << (r & 63)) - 1ULL));
            float sc = sscore[(size_t)b * TOPK + r];
            float4 bx = ((const float4*)sbox)[(size_t)b * TOPK + r];
            size_t base_o = (((size_t)b * 2 + 1) * TOPK + (size_t)rank) * 5;
            out[base_o + 0] = sc;
            out[base_o + 1] = bx.x;
            out[base_o + 2] = bx.y;
            out[base_o + 3] = bx.z;
            out[base_o + 4] = bx.w;
        }
    }
}

extern "C" void kernel_launch(void* const* d_in, const int* in_sizes, int n_in,
                              void* d_out, int out_size, void* d_ws, size_t ws_size,
                              hipStream_t stream) {
    const float* loc   = (const float*)d_in[0];
    const float* conf  = (const float*)d_in[1];
    const float* prior = (const float*)d_in[2];
    float* out = (float*)d_out;
    char* ws = (char*)d_ws;

    // ws layout (bytes) with lifetime-based aliasing into the mask region:
    //   mask   [0, 9216000)           transposed [b][w][i]; written by mask, read by sweep
    //   hist   [0, 4194304)           32*8*4096 u32 — dead after thresh (full overwrite)
    //   keys   [4194304, 4718592)     dead after rank_decode
    //   counts [4718592, 4722688)     32*CPAD u32 — dead after rank_decode
    //   tbin   [4722688, 4722816)     dead after compact
    //   sscore [9216000, 9408000)
    //   sbox   [9408000, 10176000)    total 10,176,000 B
    u64* mask_buf = (u64*)(ws + 0);
    u32* hist     = (u32*)(ws + 0);
    u64* keys     = (u64*)(ws + 4194304);
    u32* counts   = (u32*)(ws + 4718592);
    int* tbin     = (int*)(ws + 4722688);
    float* sscore = (float*)(ws + 9216000);
    float* sbox   = (float*)(ws + 9408000);

    zero_kernel<<<512, 256, 0, stream>>>(counts, NUM_B * CPAD, (u32*)out, 480000,
                                         (u32*)sscore, 240000);
    hist_kernel<<<dim3(HSLICES, 32), 256, 0, stream>>>((const float4*)conf, hist);
    thresh_kernel<<<32, 256, 0, stream>>>(hist, tbin);
    compact_kernel<<<dim3(150, 32), 256, 0, stream>>>((const float4*)conf, tbin, counts, keys);
    rank_decode_kernel<<<dim3(CAP / 256, 32), 256, 0, stream>>>(keys, counts, loc, prior,
                                                                sscore, sbox);
    mask_kernel<<<dim3(NWORDS, NCHUNK, 32), 256, 0, stream>>>(sbox, mask_buf);
    sweep_kernel<<<32, 64, 0, stream>>>(mask_buf, sscore, sbox, out);
}

// Round 12
// 197.947 us; speedup vs baseline: 1.1402x; 1.1402x over previous
//
#include <hip/hip_runtime.h>
#include <stdint.h>

typedef unsigned long long u64;
typedef unsigned int u32;

#define NUM_B 32
#define NUM_P 76800
#define TOPK 1500
#define NBINS 4096   // linear bins: bin = min(int(s*4096), 4095)
#define CAP 2048
#define NWORDS 24    // ceil(1500/64) u64 words per mask row == number of 64-row tiles
#define NCHUNK 6     // ceil(1500/256) row chunks for mask grid
#define CPAD 32      // counts padded to 128 B to kill same-line atomic serialization
#define HSLICES 8    // private histogram slices per batch (no global atomics)
#define HCHUNK (NUM_P / HSLICES)   // 9600 priors per slice

__device__ __forceinline__ u32 fbits(float f) { return __float_as_uint(f); }
// Monotone non-decreasing in s => threshold-bin selection is order-correct.
__device__ __forceinline__ int binOf(float s) {
    int b = (int)(s * (float)NBINS);
    return (b > NBINS - 1) ? NBINS - 1 : b;
}
// wave-uniform lane read of a u64 register
__device__ __forceinline__ u64 readlane64(u64 v, int l) {
    u32 lo = (u32)__builtin_amdgcn_readlane((int)(u32)(v & 0xffffffffu), l);
    u32 hi = (u32)__builtin_amdgcn_readlane((int)(u32)(v >> 32), l);
    return ((u64)hi << 32) | lo;
}

// ---------------- zero counts + output + sscore/sbox ----------------
__global__ void zero_kernel(u32* a, int n, u32* c, int nc, u32* d, int nd) {
    int i = blockIdx.x * blockDim.x + threadIdx.x;
    int stride = gridDim.x * blockDim.x;
    for (int t = i; t < n; t += stride) a[t] = 0;
    for (int t = i; t < nc; t += stride) c[t] = 0;
    for (int t = i; t < nd; t += stride) d[t] = 0;
}

// ---------------- histogram: LDS-private per (batch, slice), full overwrite ----------------
__global__ __launch_bounds__(256) void hist_kernel(const float4* __restrict__ conf4,
                                                   u32* __restrict__ hist) {
    int c = blockIdx.x, b = blockIdx.y, tid = threadIdx.x;
    __shared__ u32 h[NBINS];
    for (int i = tid; i < NBINS; i += 256) h[i] = 0;
    __syncthreads();
    const float4* base = conf4 + (size_t)b * (NUM_P / 2) + (size_t)c * (HCHUNK / 2);
    for (int i = tid; i < HCHUNK / 2; i += 256) {
        float4 v = base[i];           // 2 priors: (c0,c1,c0,c1); class-1 = .y/.w
        if (v.y > 0.01f) atomicAdd(&h[binOf(v.y)], 1u);
        if (v.w > 0.01f) atomicAdd(&h[binOf(v.w)], 1u);
    }
    __syncthreads();
    u32* outp = hist + ((size_t)b * HSLICES + c) * NBINS;
    for (int i = tid; i < NBINS; i += 256) outp[i] = h[i];
}

// ---------------- find per-batch threshold bin: smallest bin T with suffix count >= TOPK ----
__global__ void thresh_kernel(const u32* __restrict__ hist, int* __restrict__ tbin) {
    int b = blockIdx.x;
    int tid = threadIdx.x;
    const u32* hb = hist + (size_t)b * HSLICES * NBINS;
    __shared__ u32 vals[256];
    __shared__ int s_min;
    u32 total = 0;
    for (int c = 0; c < NBINS / 256; ++c) {
        if (tid == 0) s_min = 256;
        int bin = NBINS - 1 - (c * 256 + tid);
        u32 v = 0;
#pragma unroll
        for (int s = 0; s < HSLICES; ++s) v += hb[(size_t)s * NBINS + bin];
        __syncthreads();
        vals[tid] = v;
        __syncthreads();
        for (int off = 1; off < 256; off <<= 1) {
            u32 add = (tid >= off) ? vals[tid - off] : 0;
            __syncthreads();
            vals[tid] += add;
            __syncthreads();
        }
        u32 cum = total + vals[tid];
        if (cum >= TOPK) atomicMin(&s_min, tid);
        __syncthreads();
        if (s_min < 256) {
            if (tid == 0) tbin[b] = NBINS - 1 - (c * 256 + s_min);
            return;
        }
        total += vals[255];
    }
    if (tid == 0) tbin[b] = 0;
}

// ---------------- compact candidate keys: float4 loads, padded counters ----------------
__global__ __launch_bounds__(256) void compact_kernel(
    const float4* __restrict__ conf4, const int* __restrict__ tbin,
    u32* __restrict__ counts, u64* __restrict__ keys) {
    int b = blockIdx.y;
    int tid = threadIdx.x;
    int lane = tid & 63, wave = tid >> 6;
    int f4 = blockIdx.x * 256 + tid;            // float4 index within batch (2 priors)
    float4 c = conf4[(size_t)b * (NUM_P / 2) + f4];
    int tb = tbin[b];
    int p0 = f4 * 2, p1 = p0 + 1;
    bool v0 = (c.y > 0.01f) && (binOf(c.y) >= tb);
    bool v1 = (c.w > 0.01f) && (binOf(c.w) >= tb);

    u64 m0 = __ballot(v0), m1 = __ballot(v1);
    u32 c0 = (u32)__popcll(m0);
    u64 below = (1ULL << lane) - 1ULL;
    u32 off0 = (u32)__popcll(m0 & below);
    u32 off1 = c0 + (u32)__popcll(m1 & below);
    u32 wtot = c0 + (u32)__popcll(m1);

    __shared__ u32 wcnt[4];
    __shared__ u32 s_base;
    if (lane == 0) wcnt[wave] = wtot;
    __syncthreads();
    if (tid == 0) {
        u32 tot = wcnt[0] + wcnt[1] + wcnt[2] + wcnt[3];
        s_base = (tot > 0) ? atomicAdd(&counts[(size_t)b * CPAD], tot) : 0u;
    }
    __syncthreads();
    u32 woff = 0;
    for (int w = 0; w < wave; ++w) woff += wcnt[w];
    if (v0) {
        u32 pos = s_base + woff + off0;
        if (pos < CAP) keys[(size_t)b * CAP + pos] = ((u64)fbits(c.y) << 32) | (u32)(~p0);
    }
    if (v1) {
        u32 pos = s_base + woff + off1;
        if (pos < CAP) keys[(size_t)b * CAP + pos] = ((u64)fbits(c.w) << 32) | (u32)(~p1);
    }
}

// ---------------- rank-by-count (replaces bitonic sort) + gather+decode boxes ----------
__global__ __launch_bounds__(256) void rank_decode_kernel(
    const u64* __restrict__ keys, const u32* __restrict__ counts,
    const float* __restrict__ loc, const float* __restrict__ prior,
    float* __restrict__ sscore, float* __restrict__ sbox) {
#pragma clang fp contract(off)
    int blk = blockIdx.x, b = blockIdx.y, tid = threadIdx.x;
    __shared__ u64 k[CAP];
    int n = (int)min(counts[(size_t)b * CPAD], (u32)CAP);
    for (int t = tid; t < CAP; t += 256)
        k[t] = (t < n) ? keys[(size_t)b * CAP + t] : 0ULL;
    __syncthreads();

    int t = blk * 256 + tid;
    u64 mykey = k[t];
    if (mykey == 0ULL) return;   // empty slot (valid keys have score bits != 0)

    u32 rank = 0;
#pragma unroll 8
    for (int j = 0; j < CAP; ++j) rank += (k[j] > mykey) ? 1u : 0u;

    if (rank < TOPK) {
        u32 pidx = ~(u32)mykey;
        float sc = __uint_as_float((u32)(mykey >> 32));
        const float* lp = &loc[((size_t)b * NUM_P + pidx) * 4];
        const float* pp = &prior[(size_t)pidx * 4];
        float lx = lp[0], ly = lp[1], lw = lp[2], lh = lp[3];
        float pcx = pp[0], pcy = pp[1], pw = pp[2], ph = pp[3];
        float cx = pcx + (lx * 0.1f) * pw;
        float cy = pcy + (ly * 0.1f) * ph;
        float w  = pw * expf(lw * 0.2f);
        float h  = ph * expf(lh * 0.2f);
        float x1 = cx - w * 0.5f;
        float y1 = cy - h * 0.5f;
        float x2 = x1 + w;
        float y2 = y1 + h;
        sscore[(size_t)b * TOPK + rank] = sc;
        float* bx = &sbox[((size_t)b * TOPK + rank) * 4];
        bx[0] = x1; bx[1] = y1; bx[2] = x2; bx[3] = y2;
    }
}

// ---------------- NMS phase 1: suppression bitmask — transposed, balanced, div-free ----
__global__ __launch_bounds__(256) void mask_kernel(
    const float* __restrict__ sbox, u64* __restrict__ mask) {
#pragma clang fp contract(off)
    int w = blockIdx.x, c = blockIdx.y, b = blockIdx.z, tid = threadIdx.x;
    int i = c * 256 + tid;
    __shared__ float4 cbox[64];
    __shared__ float car[64];
    bool blk_live = (w * 64 + 63) > (c * 256);   // any row in chunk needs this word
    if (blk_live) {
        if (tid < 64) {
            int j = w * 64 + tid;
            float4 bx = make_float4(0.f, 0.f, 0.f, 0.f);
            if (j < TOPK) bx = ((const float4*)sbox)[(size_t)b * TOPK + j];
            cbox[tid] = bx;
            car[tid] = (bx.z - bx.x) * (bx.w - bx.y);
        }
        __syncthreads();
    }
    u64 m = 0;
    if (blk_live && i < TOPK && (w * 64 + 63) > i) {
        const double MID = 0.5 * ((double)__uint_as_float(0x3E4CCCCDu) +
                                  (double)__uint_as_float(0x3E4CCCCEu));
        const float4 bx = ((const float4*)sbox)[(size_t)b * TOPK + i];
        float x1i = bx.x, y1i = bx.y, x2i = bx.z, y2i = bx.w;
        float ai = (x2i - x1i) * (y2i - y1i);
        u64 jmask = (i < w * 64) ? ~0ULL : (~0ULL << (i - w * 64 + 1));
        for (int j2 = 0; j2 < 64; ++j2) {
            float4 cb = cbox[j2];
            float xx1 = fmaxf(cb.x, x1i);
            float yy1 = fmaxf(cb.y, y1i);
            float xx2 = fminf(cb.z, x2i);
            float yy2 = fminf(cb.w, y2i);
            float iw = fmaxf(xx2 - xx1, 0.0f);
            float ih = fmaxf(yy2 - yy1, 0.0f);
            float inter = iw * ih;
            float denom = (car[j2] + ai) - inter;
            if ((double)inter >= MID * (double)denom) m |= (1ULL << j2);
        }
        m &= jmask;
    }
    if (i < TOPK)
        mask[((size_t)b * NWORDS + w) * TOPK + i] = m;
}

// ---------------- NMS phase 2: producer/consumer sweep, one block (4 waves) per batch ----
// Wave 0 (consumer): greedy + apply from LDS only — never waits on vmcnt.
// Waves 1-3 (producers): 8 words each, triple-buffered LDS tiles, register-hop
// pipeline (round T: ds_write tile T+2 loaded last round, issue loads tile T+3)
// so global load latency is hidden by a full round and stalls only producers.
__global__ __launch_bounds__(256) void sweep_kernel(
    const u64* __restrict__ mask, const float* __restrict__ sscore,
    const float* __restrict__ sbox, float* __restrict__ out) {
    int b = blockIdx.x, tid = threadIdx.x;
    int lane = tid & 63, wid = tid >> 6;

    const u64* mbase = mask + (size_t)b * NWORDS * TOPK;   // word w, row r: mbase[w*TOPK+r]

    __shared__ u64 rowbuf[3][NWORDS][65];   // [slot][word][row(+pad)]
    __shared__ u64 aw[NWORDS];
    __shared__ u32 pfx[NWORDS + 1];

    u64 act = 0;
    u64 sv[8];
    if (wid == 0) {
        // initial active bitmap from validity (score > 0); lane w owns act word w
        for (int c = 0; c < NWORDS; ++c) {
            int r = c * 64 + lane;
            bool v = (r < TOPK) && (sscore[(size_t)b * TOPK + r] > 0.0f);
            u64 m = __ballot(v);
            if (lane == c) act = m;
        }
    } else {
        int w0 = (wid - 1) * 8;
        // stage tiles 0 and 1 (rows < 1500, no guard needed)
#pragma unroll
        for (int t = 0; t < 2; ++t) {
            u64 tmp[8];
#pragma unroll
            for (int k = 0; k < 8; ++k)
                tmp[k] = mbase[(size_t)(w0 + k) * TOPK + t * 64 + lane];
#pragma unroll
            for (int k = 0; k < 8; ++k)
                rowbuf[t][w0 + k][lane] = tmp[k];
        }
        // issue loads for tile 2 into the register hop
        {
            int rr = 2 * 64 + lane;
#pragma unroll
            for (int k = 0; k < 8; ++k)
                sv[k] = mbase[(size_t)(w0 + k) * TOPK + rr];
        }
    }
    __syncthreads();

    for (int T = 0; T < NWORDS; ++T) {
        if (wid == 0) {
            // diag word of tile T into registers (one coalesced LDS read)
            u64 dreg = rowbuf[T % 3][T][lane];
            u64 actw = readlane64(act, T);
            u64 kept = 0, rem = actw;
            while (rem) {
                int i2 = __ffsll(rem) - 1;
                kept |= (1ULL << i2);
                rem &= rem - 1;
                rem &= ~readlane64(dreg, i2);
            }
            if (lane == T) act = kept;
            // cross-tile apply: word lane of kept rows (rows < tile have 0 bits there)
            if (lane > T && lane < NWORDS) {
                u64 kb = kept;
                while (kb) {
                    int r = __ffsll(kb) - 1;
                    kb &= kb - 1;
                    act &= ~rowbuf[T % 3][lane][r];
                }
            }
        } else {
            int tw = T + 2;                 // tile whose data sits in sv (loaded last round)
            if (tw < NWORDS) {
                int w0 = (wid - 1) * 8;
#pragma unroll
                for (int k = 0; k < 8; ++k)
                    rowbuf[tw % 3][w0 + k][lane] = sv[k];
                int tn = T + 3;
                if (tn < NWORDS) {
                    int rr = tn * 64 + lane;
                    bool vr = rr < TOPK;
#pragma unroll
                    for (int k = 0; k < 8; ++k)
                        sv[k] = vr ? mbase[(size_t)(w0 + k) * TOPK + rr] : 0ULL;
                }
            }
        }
        __syncthreads();
    }

    // epilogue: act (wave 0) == keep bitmap; rank by prefix popcount, compact write
    if (wid == 0 && lane < NWORDS) aw[lane] = act;
    __syncthreads();
    if (tid == 0) {
        u32 acc = 0;
        for (int wd = 0; wd < NWORDS; ++wd) { pfx[wd] = acc; acc += (u32)__popcll(aw[wd]); }
        pfx[NWORDS] = acc;
    }
    __syncthreads();
    for (int r = tid; r < TOPK; r += 256) {
        int wd = r >> 6;
        u64 word = aw[wd];
        if ((word >> (r & 63)) & 1ULL) {
            u32 rank = pfx[wd] + (u32)__popcll(word & ((1ULL << (r & 63)) - 1ULL));
            float sc = sscore[(size_t)b * TOPK + r];
            float4 bx = ((const float4*)sbox)[(size_t)b * TOPK + r];
            size_t base_o = (((size_t)b * 2 + 1) * TOPK + (size_t)rank) * 5;
            out[base_o + 0] = sc;
            out[base_o + 1] = bx.x;
            out[base_o + 2] = bx.y;
            out[base_o + 3] = bx.z;
            out[base_o + 4] = bx.w;
        }
    }
}

extern "C" void kernel_launch(void* const* d_in, const int* in_sizes, int n_in,
                              void* d_out, int out_size, void* d_ws, size_t ws_size,
                              hipStream_t stream) {
    const float* loc   = (const float*)d_in[0];
    const float* conf  = (const float*)d_in[1];
    const float* prior = (const float*)d_in[2];
    float* out = (float*)d_out;
    char* ws = (char*)d_ws;

    // ws layout (bytes) with lifetime-based aliasing into the mask region:
    //   mask   [0, 9216000)           transposed [b][w][i]; written by mask, read by sweep
    //   hist   [0, 4194304)           32*8*4096 u32 — dead after thresh (full overwrite)
    //   keys   [4194304, 4718592)     dead after rank_decode
    //   counts [4718592, 4722688)     32*CPAD u32 — dead after rank_decode
    //   tbin   [4722688, 4722816)     dead after compact
    //   sscore [9216000, 9408000)
    //   sbox   [9408000, 10176000)    total 10,176,000 B
    u64* mask_buf = (u64*)(ws + 0);
    u32* hist     = (u32*)(ws + 0);
    u64* keys     = (u64*)(ws + 4194304);
    u32* counts   = (u32*)(ws + 4718592);
    int* tbin     = (int*)(ws + 4722688);
    float* sscore = (float*)(ws + 9216000);
    float* sbox   = (float*)(ws + 9408000);

    zero_kernel<<<512, 256, 0, stream>>>(counts, NUM_B * CPAD, (u32*)out, 480000,
                                         (u32*)sscore, 240000);
    hist_kernel<<<dim3(HSLICES, 32), 256, 0, stream>>>((const float4*)conf, hist);
    thresh_kernel<<<32, 256, 0, stream>>>(hist, tbin);
    compact_kernel<<<dim3(150, 32), 256, 0, stream>>>((const float4*)conf, tbin, counts, keys);
    rank_decode_kernel<<<dim3(CAP / 256, 32), 256, 0, stream>>>(keys, counts, loc, prior,
                                                                sscore, sbox);
    mask_kernel<<<dim3(NWORDS, NCHUNK, 32), 256, 0, stream>>>(sbox, mask_buf);
    sweep_kernel<<<32, 256, 0, stream>>>(mask_buf, sscore, sbox, out);
}

// Round 13
// 194.037 us; speedup vs baseline: 1.1632x; 1.0202x over previous
//
#include <hip/hip_runtime.h>
#include <stdint.h>

typedef unsigned long long u64;
typedef unsigned int u32;

#define NUM_B 32
#define NUM_P 76800
#define TOPK 1500
#define NBINS 4096   // linear bins: bin = min(int(s*4096), 4095)
#define CAP 2048
#define NWORDS 24    // ceil(1500/64) u64 words per mask row == number of 64-row tiles
#define NCHUNK 6     // ceil(1500/256) row chunks for mask grid
#define CPAD 32      // counts padded to 128 B to kill same-line atomic serialization
#define HSLICES 16   // private histogram slices per batch (no global atomics)
#define HCHUNK (NUM_P / HSLICES)   // 4800 priors per slice

__device__ __forceinline__ u32 fbits(float f) { return __float_as_uint(f); }
// Monotone non-decreasing in s => threshold-bin selection is order-correct.
__device__ __forceinline__ int binOf(float s) {
    int b = (int)(s * (float)NBINS);
    return (b > NBINS - 1) ? NBINS - 1 : b;
}
// wave-uniform lane read of a u64 register
__device__ __forceinline__ u64 readlane64(u64 v, int l) {
    u32 lo = (u32)__builtin_amdgcn_readlane((int)(u32)(v & 0xffffffffu), l);
    u32 hi = (u32)__builtin_amdgcn_readlane((int)(u32)(v >> 32), l);
    return ((u64)hi << 32) | lo;
}

// ---------------- histogram: LDS-private per (batch, slice); also zeroes counts ----------
__global__ __launch_bounds__(256) void hist_kernel(const float4* __restrict__ conf4,
                                                   u32* __restrict__ hist,
                                                   u32* __restrict__ counts) {
    int c = blockIdx.x, b = blockIdx.y, tid = threadIdx.x;
    if (c == 0 && tid < CPAD) counts[(size_t)b * CPAD + tid] = 0;  // compact's counter
    __shared__ u32 h[NBINS];
    for (int i = tid; i < NBINS; i += 256) h[i] = 0;
    __syncthreads();
    const float4* base = conf4 + (size_t)b * (NUM_P / 2) + (size_t)c * (HCHUNK / 2);
    for (int i = tid; i < HCHUNK / 2; i += 256) {
        float4 v = base[i];           // 2 priors: (c0,c1,c0,c1); class-1 = .y/.w
        if (v.y > 0.01f) atomicAdd(&h[binOf(v.y)], 1u);
        if (v.w > 0.01f) atomicAdd(&h[binOf(v.w)], 1u);
    }
    __syncthreads();
    u32* outp = hist + ((size_t)b * HSLICES + c) * NBINS;
    for (int i = tid; i < NBINS; i += 256) outp[i] = h[i];
}

// ---------------- find per-batch threshold bin: smallest bin T with suffix count >= TOPK ----
__global__ void thresh_kernel(const u32* __restrict__ hist, int* __restrict__ tbin) {
    int b = blockIdx.x;
    int tid = threadIdx.x;
    const u32* hb = hist + (size_t)b * HSLICES * NBINS;
    __shared__ u32 vals[256];
    __shared__ int s_min;
    u32 total = 0;
    for (int c = 0; c < NBINS / 256; ++c) {
        if (tid == 0) s_min = 256;
        int bin = NBINS - 1 - (c * 256 + tid);
        u32 v = 0;
#pragma unroll
        for (int s = 0; s < HSLICES; ++s) v += hb[(size_t)s * NBINS + bin];
        __syncthreads();
        vals[tid] = v;
        __syncthreads();
        for (int off = 1; off < 256; off <<= 1) {
            u32 add = (tid >= off) ? vals[tid - off] : 0;
            __syncthreads();
            vals[tid] += add;
            __syncthreads();
        }
        u32 cum = total + vals[tid];
        if (cum >= TOPK) atomicMin(&s_min, tid);
        __syncthreads();
        if (s_min < 256) {
            if (tid == 0) tbin[b] = NBINS - 1 - (c * 256 + s_min);
            return;
        }
        total += vals[255];
    }
    if (tid == 0) tbin[b] = 0;
}

// ---------------- compact candidate keys: float4 loads, padded counters ----------------
__global__ __launch_bounds__(256) void compact_kernel(
    const float4* __restrict__ conf4, const int* __restrict__ tbin,
    u32* __restrict__ counts, u64* __restrict__ keys) {
    int b = blockIdx.y;
    int tid = threadIdx.x;
    int lane = tid & 63, wave = tid >> 6;
    int f4 = blockIdx.x * 256 + tid;            // float4 index within batch (2 priors)
    float4 c = conf4[(size_t)b * (NUM_P / 2) + f4];
    int tb = tbin[b];
    int p0 = f4 * 2, p1 = p0 + 1;
    bool v0 = (c.y > 0.01f) && (binOf(c.y) >= tb);
    bool v1 = (c.w > 0.01f) && (binOf(c.w) >= tb);

    u64 m0 = __ballot(v0), m1 = __ballot(v1);
    u32 c0 = (u32)__popcll(m0);
    u64 below = (1ULL << lane) - 1ULL;
    u32 off0 = (u32)__popcll(m0 & below);
    u32 off1 = c0 + (u32)__popcll(m1 & below);
    u32 wtot = c0 + (u32)__popcll(m1);

    __shared__ u32 wcnt[4];
    __shared__ u32 s_base;
    if (lane == 0) wcnt[wave] = wtot;
    __syncthreads();
    if (tid == 0) {
        u32 tot = wcnt[0] + wcnt[1] + wcnt[2] + wcnt[3];
        s_base = (tot > 0) ? atomicAdd(&counts[(size_t)b * CPAD], tot) : 0u;
    }
    __syncthreads();
    u32 woff = 0;
    for (int w = 0; w < wave; ++w) woff += wcnt[w];
    if (v0) {
        u32 pos = s_base + woff + off0;
        if (pos < CAP) keys[(size_t)b * CAP + pos] = ((u64)fbits(c.y) << 32) | (u32)(~p0);
    }
    if (v1) {
        u32 pos = s_base + woff + off1;
        if (pos < CAP) keys[(size_t)b * CAP + pos] = ((u64)fbits(c.w) << 32) | (u32)(~p1);
    }
}

// ---------------- rank-by-count + gather+decode boxes ----------------
// Threshold bin guarantees n >= TOPK, so every rank 0..TOPK-1 is written:
// no zero-init of sscore/sbox needed.
__global__ __launch_bounds__(256) void rank_decode_kernel(
    const u64* __restrict__ keys, const u32* __restrict__ counts,
    const float* __restrict__ loc, const float* __restrict__ prior,
    float* __restrict__ sscore, float* __restrict__ sbox) {
#pragma clang fp contract(off)
    int blk = blockIdx.x, b = blockIdx.y, tid = threadIdx.x;
    __shared__ u64 k[CAP];
    int n = (int)min(counts[(size_t)b * CPAD], (u32)CAP);
    for (int t = tid; t < CAP; t += 256)
        k[t] = (t < n) ? keys[(size_t)b * CAP + t] : 0ULL;
    __syncthreads();

    int t = blk * 256 + tid;
    u64 mykey = k[t];
    if (mykey == 0ULL) return;   // empty slot (valid keys have score bits != 0)

    u32 rank = 0;
#pragma unroll 8
    for (int j = 0; j < CAP; ++j) rank += (k[j] > mykey) ? 1u : 0u;

    if (rank < TOPK) {
        u32 pidx = ~(u32)mykey;
        float sc = __uint_as_float((u32)(mykey >> 32));
        const float* lp = &loc[((size_t)b * NUM_P + pidx) * 4];
        const float* pp = &prior[(size_t)pidx * 4];
        float lx = lp[0], ly = lp[1], lw = lp[2], lh = lp[3];
        float pcx = pp[0], pcy = pp[1], pw = pp[2], ph = pp[3];
        float cx = pcx + (lx * 0.1f) * pw;
        float cy = pcy + (ly * 0.1f) * ph;
        float w  = pw * expf(lw * 0.2f);
        float h  = ph * expf(lh * 0.2f);
        float x1 = cx - w * 0.5f;
        float y1 = cy - h * 0.5f;
        float x2 = x1 + w;
        float y2 = y1 + h;
        sscore[(size_t)b * TOPK + rank] = sc;
        float* bx = &sbox[((size_t)b * TOPK + rank) * 4];
        bx[0] = x1; bx[1] = y1; bx[2] = x2; bx[3] = y2;
    }
}

// ---------------- NMS phase 1: suppression bitmask — transposed, balanced, div-free ----
// Dead blocks exit before staging. Rows store only words w >= tile(i): the sweep
// consumer provably never reads words < T of tile-T rows (greedy uses word T,
// apply uses words lane > T), so unwritten (poisoned) slots are never consumed.
__global__ __launch_bounds__(256) void mask_kernel(
    const float* __restrict__ sbox, u64* __restrict__ mask) {
#pragma clang fp contract(off)
    int w = blockIdx.x, c = blockIdx.y, b = blockIdx.z, tid = threadIdx.x;
    int i = c * 256 + tid;
    if ((w * 64 + 63) <= (c * 256)) return;   // whole chunk dead: no store at all
    __shared__ float4 cbox[64];
    __shared__ float car[64];
    if (tid < 64) {
        int j = w * 64 + tid;
        float4 bx = make_float4(0.f, 0.f, 0.f, 0.f);
        if (j < TOPK) bx = ((const float4*)sbox)[(size_t)b * TOPK + j];
        cbox[tid] = bx;
        car[tid] = (bx.z - bx.x) * (bx.w - bx.y);
    }
    __syncthreads();
    if (i < TOPK && (w * 64 + 63) > i) {
        const double MID = 0.5 * ((double)__uint_as_float(0x3E4CCCCDu) +
                                  (double)__uint_as_float(0x3E4CCCCEu));
        const float4 bx = ((const float4*)sbox)[(size_t)b * TOPK + i];
        float x1i = bx.x, y1i = bx.y, x2i = bx.z, y2i = bx.w;
        float ai = (x2i - x1i) * (y2i - y1i);
        u64 jmask = (i < w * 64) ? ~0ULL : (~0ULL << (i - w * 64 + 1));
        u64 m = 0;
        for (int j2 = 0; j2 < 64; ++j2) {
            float4 cb = cbox[j2];
            float xx1 = fmaxf(cb.x, x1i);
            float yy1 = fmaxf(cb.y, y1i);
            float xx2 = fminf(cb.z, x2i);
            float yy2 = fminf(cb.w, y2i);
            float iw = fmaxf(xx2 - xx1, 0.0f);
            float ih = fmaxf(yy2 - yy1, 0.0f);
            float inter = iw * ih;
            float denom = (car[j2] + ai) - inter;
            if ((double)inter >= MID * (double)denom) m |= (1ULL << j2);
        }
        m &= jmask;
        mask[((size_t)b * NWORDS + w) * TOPK + i] = m;
    }
}

// ---------------- NMS phase 2: producer/consumer sweep, one block (4 waves) per batch ----
// Wave 0 (consumer): greedy + apply from LDS only — never waits on vmcnt.
// Waves 1-3 (producers): 8 words each, triple-buffered LDS tiles, register-hop
// pipeline; loads of words w < tile are skipped (those slots never consumed).
// Epilogue zeroes both output planes (replaces zero_kernel) then scatters.
__global__ __launch_bounds__(256) void sweep_kernel(
    const u64* __restrict__ mask, const float* __restrict__ sscore,
    const float* __restrict__ sbox, float* __restrict__ out) {
    int b = blockIdx.x, tid = threadIdx.x;
    int lane = tid & 63, wid = tid >> 6;

    const u64* mbase = mask + (size_t)b * NWORDS * TOPK;   // word w, row r: mbase[w*TOPK+r]

    __shared__ u64 rowbuf[3][NWORDS][65];   // [slot][word][row(+pad)]
    __shared__ u64 aw[NWORDS];
    __shared__ u32 pfx[NWORDS + 1];

    u64 act = 0;
    u64 sv[8];
    if (wid == 0) {
        // initial active bitmap from validity (score > 0); lane w owns act word w
        for (int c = 0; c < NWORDS; ++c) {
            int r = c * 64 + lane;
            bool v = (r < TOPK) && (sscore[(size_t)b * TOPK + r] > 0.0f);
            u64 m = __ballot(v);
            if (lane == c) act = m;
        }
    } else {
        int w0 = (wid - 1) * 8;
        // stage tiles 0 and 1 (rows < 1500; only words w >= tile are valid in mem)
#pragma unroll
        for (int t = 0; t < 2; ++t) {
            u64 tmp[8];
#pragma unroll
            for (int k = 0; k < 8; ++k)
                tmp[k] = (w0 + k >= t) ? mbase[(size_t)(w0 + k) * TOPK + t * 64 + lane] : 0ULL;
#pragma unroll
            for (int k = 0; k < 8; ++k)
                rowbuf[t][w0 + k][lane] = tmp[k];
        }
        // issue loads for tile 2 into the register hop
        {
            int rr = 2 * 64 + lane;
#pragma unroll
            for (int k = 0; k < 8; ++k)
                sv[k] = (w0 + k >= 2) ? mbase[(size_t)(w0 + k) * TOPK + rr] : 0ULL;
        }
    }
    __syncthreads();

    for (int T = 0; T < NWORDS; ++T) {
        if (wid == 0) {
            // diag word of tile T into registers (one coalesced LDS read)
            u64 dreg = rowbuf[T % 3][T][lane];
            u64 actw = readlane64(act, T);
            u64 kept = 0, rem = actw;
            while (rem) {
                int i2 = __ffsll(rem) - 1;
                kept |= (1ULL << i2);
                rem &= rem - 1;
                rem &= ~readlane64(dreg, i2);
            }
            if (lane == T) act = kept;
            // cross-tile apply: word lane of kept rows
            if (lane > T && lane < NWORDS) {
                u64 kb = kept;
                while (kb) {
                    int r = __ffsll(kb) - 1;
                    kb &= kb - 1;
                    act &= ~rowbuf[T % 3][lane][r];
                }
            }
        } else {
            int tw = T + 2;                 // tile whose data sits in sv (loaded last round)
            if (tw < NWORDS) {
                int w0 = (wid - 1) * 8;
#pragma unroll
                for (int k = 0; k < 8; ++k)
                    rowbuf[tw % 3][w0 + k][lane] = sv[k];
                int tn = T + 3;
                if (tn < NWORDS) {
                    int rr = tn * 64 + lane;
                    bool vr = rr < TOPK;
#pragma unroll
                    for (int k = 0; k < 8; ++k)
                        sv[k] = (vr && (w0 + k >= tn))
                                    ? mbase[(size_t)(w0 + k) * TOPK + rr] : 0ULL;
                }
            }
        }
        __syncthreads();
    }

    // epilogue: zero both output planes (replaces zero_kernel), then compact write
    if (wid == 0 && lane < NWORDS) aw[lane] = act;
    {
        float* p0 = out + ((size_t)b * 2 + 0) * TOPK * 5;
        float* p1 = out + ((size_t)b * 2 + 1) * TOPK * 5;
        for (int t = tid; t < TOPK * 5; t += 256) { p0[t] = 0.0f; p1[t] = 0.0f; }
    }
    __syncthreads();
    if (tid == 0) {
        u32 acc = 0;
        for (int wd = 0; wd < NWORDS; ++wd) { pfx[wd] = acc; acc += (u32)__popcll(aw[wd]); }
        pfx[NWORDS] = acc;
    }
    __syncthreads();
    for (int r = tid; r < TOPK; r += 256) {
        int wd = r >> 6;
        u64 word = aw[wd];
        if ((word >> (r & 63)) & 1ULL) {
            u32 rank = pfx[wd] + (u32)__popcll(word & ((1ULL << (r & 63)) - 1ULL));
            float sc = sscore[(size_t)b * TOPK + r];
            float4 bx = ((const float4*)sbox)[(size_t)b * TOPK + r];
            size_t base_o = (((size_t)b * 2 + 1) * TOPK + (size_t)rank) * 5;
            out[base_o + 0] = sc;
            out[base_o + 1] = bx.x;
            out[base_o + 2] = bx.y;
            out[base_o + 3] = bx.z;
            out[base_o + 4] = bx.w;
        }
    }
}

extern "C" void kernel_launch(void* const* d_in, const int* in_sizes, int n_in,
                              void* d_out, int out_size, void* d_ws, size_t ws_size,
                              hipStream_t stream) {
    const float* loc   = (const float*)d_in[0];
    const float* conf  = (const float*)d_in[1];
    const float* prior = (const float*)d_in[2];
    float* out = (float*)d_out;
    char* ws = (char*)d_ws;

    // ws layout (bytes) with lifetime-based aliasing into the mask region:
    //   mask   [0, 9216000)           transposed [b][w][i]; written by mask, read by sweep
    //   hist   [0, 8388608)           32*16*4096 u32 — dead after thresh (full overwrite)
    //   keys   [8388608, 8912896)     dead after rank_decode
    //   counts [8912896, 8916992)     32*CPAD u32 — dead after rank_decode
    //   tbin   [8916992, 8917120)     dead after compact
    //   sscore [9216000, 9408000)
    //   sbox   [9408000, 10176000)    total 10,176,000 B
    u64* mask_buf = (u64*)(ws + 0);
    u32* hist     = (u32*)(ws + 0);
    u64* keys     = (u64*)(ws + 8388608);
    u32* counts   = (u32*)(ws + 8912896);
    int* tbin     = (int*)(ws + 8916992);
    float* sscore = (float*)(ws + 9216000);
    float* sbox   = (float*)(ws + 9408000);

    hist_kernel<<<dim3(HSLICES, 32), 256, 0, stream>>>((const float4*)conf, hist, counts);
    thresh_kernel<<<32, 256, 0, stream>>>(hist, tbin);
    compact_kernel<<<dim3(150, 32), 256, 0, stream>>>((const float4*)conf, tbin, counts, keys);
    rank_decode_kernel<<<dim3(CAP / 256, 32), 256, 0, stream>>>(keys, counts, loc, prior,
                                                                sscore, sbox);
    mask_kernel<<<dim3(NWORDS, NCHUNK, 32), 256, 0, stream>>>(sbox, mask_buf);
    sweep_kernel<<<32, 256, 0, stream>>>(mask_buf, sscore, sbox, out);
}